// Round 11
// baseline (3742.713 us; speedup 1.0000x reference)
//
#include <hip/hip_runtime.h>
#include <hip/hip_bf16.h>
#include <stdint.h>

// Problem constants
#define T_STEPS 512
#define BATCH   64
#define IN_DIM  128
#define HID     1024
#define KTOT    (HID + IN_DIM)   // 1152: [H | X] vs [W_hh ; W_ih]
#define NWAVES  4
#define THREADS (NWAVES * 64)

// 16 WGs x 64 h-cols (4 ct tiles of 16). Wave w owns batch rows [16w,16w+16).
// No LDS H tile: per-wave register loads (r7 structure) -> no loop barriers;
// coherent read volume = 64 waves x 32 KB = 2 MB/step (vs 4 MB in r10).
#define NWG     16
#define NCOLS   64
#define NCT     4                // col sub-tiles per WG
#define NKK     36               // K-steps of 32 (1152/32)
#define LDSB    (KTOT * NCOLS * 2)   // 147456 B -> fits 160 KB, 1 WG/CU

#define RING    16               // comm ring slots (2 MB)
#define DCLR    4                // clear-ahead depth
#define SLOT    (BATCH * HID)    // 65536 bf16 = 128 KB per slot
#define SENT    0x7F7F7F7F      // bf16 pair 3.39e38, unreachable by tanh
#define NFLAGS  (NWG * NWAVES * NWG)   // 1024 ints

typedef float f32x4 __attribute__((ext_vector_type(4)));
typedef int   i32x4 __attribute__((ext_vector_type(4)));
typedef short s16x8 __attribute__((ext_vector_type(8)));
typedef uint32_t u32x2 __attribute__((ext_vector_type(2)));

#define MFMA16 __builtin_amdgcn_mfma_f32_16x16x32_bf16

__device__ __forceinline__ uint32_t cvt_pk_bf16(float a, float b) {
    uint32_t r;
    asm("v_cvt_pk_bf16_f32 %0, %1, %2" : "=v"(r) : "v"(a), "v"(b));
    return r;   // low16 = bf16(a), high16 = bf16(b)
}

union frag_u { uint32_t u[4]; s16x8 s; };

__device__ __forceinline__ s16x8 pack_bf16x8(f32x4 a, f32x4 b) {
    frag_u f;
    f.u[0] = cvt_pk_bf16(a.x, a.y);
    f.u[1] = cvt_pk_bf16(a.z, a.w);
    f.u[2] = cvt_pk_bf16(b.x, b.y);
    f.u[3] = cvt_pk_bf16(b.z, b.w);
    return f.s;
}

__device__ __forceinline__ uint16_t f32_to_bf16(float v) {
    uint32_t u = __builtin_bit_cast(uint32_t, v);
    return (uint16_t)((u + 0x7FFFu + ((u >> 16) & 1u)) >> 16);
}

// fast tanh: 1 - 2/(e^{2x}+1); saturates correctly for |x| large
__device__ __forceinline__ float tanh_fast(float x) {
    float e = __expf(2.0f * x);
    return 1.0f - 2.0f * __builtin_amdgcn_rcpf(e + 1.0f);
}

__device__ __forceinline__ int imax(int a, int b) { return a > b ? a : b; }
__device__ __forceinline__ int max4(f32x4 v) {
    i32x4 a = __builtin_bit_cast(i32x4, v);
    return imax(imax(a.x, a.y), imax(a.z, a.w));
}

// 16 pipelined coherent 16B loads from one base pointer (r7-proven).
#define GLD16(D, P, TAIL)                                               \
    asm volatile(                                                       \
        "global_load_dwordx4 %0, %16, off sc0 sc1\n\t"                  \
        "global_load_dwordx4 %1, %16, off offset:64 sc0 sc1\n\t"        \
        "global_load_dwordx4 %2, %16, off offset:128 sc0 sc1\n\t"       \
        "global_load_dwordx4 %3, %16, off offset:192 sc0 sc1\n\t"       \
        "global_load_dwordx4 %4, %16, off offset:256 sc0 sc1\n\t"       \
        "global_load_dwordx4 %5, %16, off offset:320 sc0 sc1\n\t"       \
        "global_load_dwordx4 %6, %16, off offset:384 sc0 sc1\n\t"       \
        "global_load_dwordx4 %7, %16, off offset:448 sc0 sc1\n\t"       \
        "global_load_dwordx4 %8, %16, off offset:512 sc0 sc1\n\t"       \
        "global_load_dwordx4 %9, %16, off offset:576 sc0 sc1\n\t"       \
        "global_load_dwordx4 %10, %16, off offset:640 sc0 sc1\n\t"      \
        "global_load_dwordx4 %11, %16, off offset:704 sc0 sc1\n\t"      \
        "global_load_dwordx4 %12, %16, off offset:768 sc0 sc1\n\t"      \
        "global_load_dwordx4 %13, %16, off offset:832 sc0 sc1\n\t"      \
        "global_load_dwordx4 %14, %16, off offset:896 sc0 sc1\n\t"      \
        "global_load_dwordx4 %15, %16, off offset:960 sc0 sc1" TAIL     \
        : "=&v"(D[0]), "=&v"(D[1]), "=&v"(D[2]), "=&v"(D[3]),           \
          "=&v"(D[4]), "=&v"(D[5]), "=&v"(D[6]), "=&v"(D[7]),           \
          "=&v"(D[8]), "=&v"(D[9]), "=&v"(D[10]), "=&v"(D[11]),         \
          "=&v"(D[12]), "=&v"(D[13]), "=&v"(D[14]), "=&v"(D[15])        \
        : "v"(P)                                                        \
        : "memory")

// 4-ct MFMA step: reads 4 W fragments at compile-time offsets, accumulates
// into named accs (static indexing, rule #20).
#define MM4(AF, KIDX)                                                        \
    { s16x8 _w0 = *(const s16x8*)(wfb + ((size_t)(0 * NKK + (KIDX)) << 10)); \
      s16x8 _w1 = *(const s16x8*)(wfb + ((size_t)(1 * NKK + (KIDX)) << 10)); \
      s16x8 _w2 = *(const s16x8*)(wfb + ((size_t)(2 * NKK + (KIDX)) << 10)); \
      s16x8 _w3 = *(const s16x8*)(wfb + ((size_t)(3 * NKK + (KIDX)) << 10)); \
      if ((KIDX) & 1) {                                                      \
          a01 = MFMA16(_w0, AF, a01, 0, 0, 0);                               \
          a11 = MFMA16(_w1, AF, a11, 0, 0, 0);                               \
          a21 = MFMA16(_w2, AF, a21, 0, 0, 0);                               \
          a31 = MFMA16(_w3, AF, a31, 0, 0, 0);                               \
      } else {                                                               \
          a00 = MFMA16(_w0, AF, a00, 0, 0, 0);                               \
          a10 = MFMA16(_w1, AF, a10, 0, 0, 0);                               \
          a20 = MFMA16(_w2, AF, a20, 0, 0, 0);                               \
          a30 = MFMA16(_w3, AF, a30, 0, 0, 0);                               \
      } }

#define TANH4(VO, A0, A1, BV)                                                \
    VO.x = tanh_fast(A0[0] + A1[0] + BV.x);                                  \
    VO.y = tanh_fast(A0[1] + A1[1] + BV.y);                                  \
    VO.z = tanh_fast(A0[2] + A1[2] + BV.z);                                  \
    VO.w = tanh_fast(A0[3] + A1[3] + BV.w);

__global__ void rnn_init_kernel(const float* __restrict__ H0,
                                uint16_t* __restrict__ comm) {
    // slot 0 of the ring holds bf16(H0), read by step t=0
    int i = blockIdx.x * 256 + threadIdx.x;
    for (int e = i; e < SLOT; e += 64 * 256)
        comm[e] = f32_to_bf16(H0[e]);
}

__global__ __launch_bounds__(THREADS, 1)
void rnn_seq_kernel(const float* __restrict__ X, const float* __restrict__ Wih,
                    const float* __restrict__ Whh, const float* __restrict__ bh,
                    float* __restrict__ out, uint16_t* __restrict__ comm,
                    int* __restrict__ flags2)
{
    // Full W slice [KTOT x 64] in LDS, MFMA-fragment order with ct dim:
    // element (k, c2): ct=c2>>4, c=c2&15, at byte ((ct*NKK + (k>>5))<<10)
    // + ((k>>3)&3)<<8 + c<<4 + (k&7)<<1. Lane-linear reads, bijective.
    extern __shared__ char lds[];

    const int tid = threadIdx.x;
    const int p   = blockIdx.x;          // WG col-slice index
    const int hc0 = p * NCOLS;

    for (int e = tid; e < NCOLS * KTOT; e += THREADS) {
        int c2 = e & 63;
        int k  = e >> 6;
        int ct = c2 >> 4, c = c2 & 15;
        float w = (k < HID) ? Whh[(size_t)k * HID + hc0 + c2]
                            : Wih[(size_t)(k - HID) * HID + hc0 + c2];
        uint32_t off = ((uint32_t)(ct * NKK + (k >> 5)) << 10)
                     + (((k >> 3) & 3) << 8) + (c << 4) + ((k & 7) << 1);
        *(uint16_t*)(lds + off) = f32_to_bf16(w);
    }
    __syncthreads();

    const int lane = tid & 63, wv = tid >> 6;
    const int cb = lane & 15, kg = lane >> 4;
    const int b  = wv * 16 + cb;             // batch row this lane loads/owns
    const char* wfb = lds + lane * 16;       // per-lane fragment base

    // D = mfma(Wf, Hf): rows = h (kg*4+r), cols = batch (cb). Lane owns
    // h = hc0 + ct*16 + kg*4 + {0..3} of batch b, per ct.
    const f32x4 bv0 = *(const f32x4*)(bh + hc0 + 0 * 16 + kg * 4);
    const f32x4 bv1 = *(const f32x4*)(bh + hc0 + 1 * 16 + kg * 4);
    const f32x4 bv2 = *(const f32x4*)(bh + hc0 + 2 * 16 + kg * 4);
    const f32x4 bv3 = *(const f32x4*)(bh + hc0 + 3 * 16 + kg * 4);

    // transposed private flags: cell [consumer p'][wave w][producer p].
    // The 4 w-chains are independent (disjoint rows/flags/comm bytes).
    const int* fpoll = flags2 + (p * NWAVES + wv) * NWG + (lane & 15);
    int* fst = flags2 + ((lane & 15) * NWAVES + wv) * NWG + p;

    const uint16_t* rb = comm + (size_t)b * HID + kg * 8;       // consumer base
    uint16_t* wbase = comm + (size_t)b * HID + hc0 + kg * 4;    // producer base
    float* obase = out + (size_t)b * HID + hc0 + kg * 4;

    u32x2 sentv; sentv.x = SENT; sentv.y = SENT;

    for (int t = 0; t < T_STEPS; ++t) {
        f32x4 a00 = {0.f,0.f,0.f,0.f}, a01 = {0.f,0.f,0.f,0.f};
        f32x4 a10 = {0.f,0.f,0.f,0.f}, a11 = {0.f,0.f,0.f,0.f};
        f32x4 a20 = {0.f,0.f,0.f,0.f}, a21 = {0.f,0.f,0.f,0.f};
        f32x4 a30 = {0.f,0.f,0.f,0.f}, a31 = {0.f,0.f,0.f,0.f};

        // ---- Phase A: X projection (independent; overlaps producer wait) ----
        const float* xrow = X + ((size_t)t * BATCH + b) * IN_DIM;
        #pragma unroll
        for (int kk = 0; kk < 4; ++kk) {
            int kidx = kk * 32 + kg * 8;
            f32x4 f0 = *(const f32x4*)(xrow + kidx);
            f32x4 f1 = *(const f32x4*)(xrow + kidx + 4);
            s16x8 xf = pack_bf16x8(f0, f1);
            MM4(xf, 32 + kk);
        }
        __builtin_amdgcn_sched_barrier(0);   // pin Phase A before the poll

        // ---- Phase B: private-line flag poll (16 producers of my w-chain) ----
        if (t > 0) {
            for (;;) {
                int f;
                asm volatile("global_load_dword %0, %1, off sc0 sc1\n\t"
                             "s_waitcnt vmcnt(0)"
                             : "=v"(f) : "v"(fpoll) : "memory");
                if (__all(f >= t)) break;
            }
        }
        // drain vm queue so GLD16's vmcnt counts are exact -- do not remove.
        asm volatile("s_waitcnt vmcnt(0)" ::: "memory");
        __builtin_amdgcn_sched_barrier(0);

        // ---- Phase C: load my row's H[t] (K=1024) to regs; sentinel-check ----
        const uint16_t* pr = rb + (size_t)(t & (RING - 1)) * SLOT;
        f32x4 LA[16], LB[16];
        for (;;) {
            GLD16(LA, pr, "");                               // 16 in flight
            GLD16(LB, pr + 512, "\n\ts_waitcnt vmcnt(16)");  // drain thru LA
            __builtin_amdgcn_sched_barrier(0);               // LA regs valid
            int m = (int)0x80000000;
            #pragma unroll
            for (int i = 0; i < 16; ++i) m = imax(m, max4(LA[i]));
            asm volatile("s_waitcnt vmcnt(0)" ::: "memory"); // LB regs valid
            __builtin_amdgcn_sched_barrier(0);
            #pragma unroll
            for (int i = 0; i < 16; ++i) m = imax(m, max4(LB[i]));
            if (__all(m != (int)SENT)) break;
        }

        // ---- recurrent GEMM: K=1024 x 64 cols (4 ct tiles), 128 MFMA ----
        #pragma unroll
        for (int i = 0; i < 16; ++i) {
            s16x8 af = __builtin_bit_cast(s16x8, LA[i]);
            MM4(af, i);
        }
        #pragma unroll
        for (int i = 0; i < 16; ++i) {
            s16x8 af = __builtin_bit_cast(s16x8, LB[i]);
            MM4(af, 16 + i);
        }

        // ---- Epilogue: bias+tanh; publish 4x8B; drain; flag; clear; out ----
        f32x4 vo0, vo1, vo2, vo3;
        TANH4(vo0, a00, a01, bv0)
        TANH4(vo1, a10, a11, bv1)
        TANH4(vo2, a20, a21, bv2)
        TANH4(vo3, a30, a31, bv3)

        uint16_t* pw = wbase + (size_t)((t + 1) & (RING - 1)) * SLOT;
        {
            u32x2 cd;
            cd.x = cvt_pk_bf16(vo0.x, vo0.y); cd.y = cvt_pk_bf16(vo0.z, vo0.w);
            asm volatile("global_store_dwordx2 %0, %1, off sc0 sc1" :: "v"(pw), "v"(cd) : "memory");
            cd.x = cvt_pk_bf16(vo1.x, vo1.y); cd.y = cvt_pk_bf16(vo1.z, vo1.w);
            asm volatile("global_store_dwordx2 %0, %1, off sc0 sc1" :: "v"(pw + 16), "v"(cd) : "memory");
            cd.x = cvt_pk_bf16(vo2.x, vo2.y); cd.y = cvt_pk_bf16(vo2.z, vo2.w);
            asm volatile("global_store_dwordx2 %0, %1, off sc0 sc1" :: "v"(pw + 32), "v"(cd) : "memory");
            cd.x = cvt_pk_bf16(vo3.x, vo3.y); cd.y = cvt_pk_bf16(vo3.z, vo3.w);
            asm volatile("global_store_dwordx2 %0, %1, off sc0 sc1" :: "v"(pw + 48), "v"(cd) : "memory");
        }
        // drain publishes so the flag can't outrun the data (sentinels remain
        // as backstop); then flag, then clears (drained by next-iter vmcnt(0))
        asm volatile("s_waitcnt vmcnt(0)" ::: "memory");
        if (lane < 16) {
            int fv = t + 1;
            asm volatile("global_store_dword %0, %1, off sc0 sc1"
                         :: "v"(fst), "v"(fv) : "memory");
        }
        {
            uint16_t* pc = wbase + (size_t)((t + 1 + DCLR) & (RING - 1)) * SLOT;
            asm volatile("global_store_dwordx2 %0, %1, off sc0 sc1" :: "v"(pc), "v"(sentv) : "memory");
            asm volatile("global_store_dwordx2 %0, %1, off sc0 sc1" :: "v"(pc + 16), "v"(sentv) : "memory");
            asm volatile("global_store_dwordx2 %0, %1, off sc0 sc1" :: "v"(pc + 32), "v"(sentv) : "memory");
            asm volatile("global_store_dwordx2 %0, %1, off sc0 sc1" :: "v"(pc + 48), "v"(sentv) : "memory");
        }

        // fp32 states (normal cached 16B stores, off the critical path)
        float* po = obase + (size_t)t * BATCH * HID;
        *(f32x4*)(po)      = vo0;
        *(f32x4*)(po + 16) = vo1;
        *(f32x4*)(po + 32) = vo2;
        *(f32x4*)(po + 48) = vo3;
        if (t == T_STEPS - 1) {
            float* pf = obase + (size_t)T_STEPS * BATCH * HID;
            *(f32x4*)(pf)      = vo0;
            *(f32x4*)(pf + 16) = vo1;
            *(f32x4*)(pf + 32) = vo2;
            *(f32x4*)(pf + 48) = vo3;
        }
    }
}

extern "C" void kernel_launch(void* const* d_in, const int* in_sizes, int n_in,
                              void* d_out, int out_size, void* d_ws, size_t ws_size,
                              hipStream_t stream) {
    (void)in_sizes; (void)n_in; (void)out_size; (void)ws_size;
    const float* X   = (const float*)d_in[0];
    const float* Wih = (const float*)d_in[1];
    const float* Whh = (const float*)d_in[2];
    const float* bh  = (const float*)d_in[3];
    const float* H0  = (const float*)d_in[4];
    float* out = (float*)d_out;

    uint16_t* comm = (uint16_t*)d_ws;                             // 2 MB ring
    int* flags2 = (int*)((char*)d_ws + (size_t)RING * SLOT * 2);  // 1024 ints

    hipFuncSetAttribute((const void*)rnn_seq_kernel,
                        hipFuncAttributeMaxDynamicSharedMemorySize, LDSB);

    // sentinel-fill the ring, zero the flags, then bf16(H0) -> slot 0
    hipMemsetAsync(comm, 0x7F, (size_t)RING * SLOT * 2, stream);
    hipMemsetAsync(flags2, 0, NFLAGS * sizeof(int), stream);
    hipLaunchKernelGGL(rnn_init_kernel, dim3(64), dim3(256), 0, stream, H0, comm);
    hipLaunchKernelGGL(rnn_seq_kernel, dim3(NWG), dim3(THREADS), LDSB, stream,
                       X, Wih, Whh, bh, out, comm, flags2);
}

// Round 12
// 2059.974 us; speedup vs baseline: 1.8169x; 1.8169x over previous
//
#include <hip/hip_runtime.h>
#include <hip/hip_bf16.h>
#include <stdint.h>

// Problem constants
#define T_STEPS 512
#define BATCH   64
#define IN_DIM  128
#define HID     1024
#define KTOT    (HID + IN_DIM)   // 1152
#define NWAVES  4
#define THREADS (NWAVES * 64)

// 4 independent batch-groups x 16 col-slices. WG = 16 batches x 64 cols.
// Wave w: 16 batches x 16 cols, W in VGPRs (36 frags = 144 regs).
// Group H tile (16 x 1024 bf16 = 32 KB) double-buffered in LDS, shared.
#define NGRP    4
#define NSL     16               // col-slice WGs per group
#define NB      16               // batches per group
#define NKH     32               // recurrent K-steps (1024/32)
#define NKX     4                // X K-steps (128/32)
#define HBUF    32768            // one H LDS buffer
#define LDSB    73728            // W-stage scratch (also covers 2x32KB H)

#define RING    16               // comm ring slots (2 MB)
#define DCLR    4                // clear-ahead depth
#define SLOT    (BATCH * HID)    // 65536 bf16 = 128 KB per slot
#define SENT    0x7F7F7F7F      // bf16 pair 3.39e38, unreachable by tanh
#define NFLAGS  (NGRP * NSL * NWAVES * 64)   // 16384 ints

typedef float f32x4 __attribute__((ext_vector_type(4)));
typedef int   i32x4 __attribute__((ext_vector_type(4)));
typedef short s16x8 __attribute__((ext_vector_type(8)));
typedef uint32_t u32x2 __attribute__((ext_vector_type(2)));

#define MFMA16 __builtin_amdgcn_mfma_f32_16x16x32_bf16

__device__ __forceinline__ uint32_t cvt_pk_bf16(float a, float b) {
    uint32_t r;
    asm("v_cvt_pk_bf16_f32 %0, %1, %2" : "=v"(r) : "v"(a), "v"(b));
    return r;   // low16 = bf16(a), high16 = bf16(b)
}

union frag_u { uint32_t u[4]; s16x8 s; };

__device__ __forceinline__ s16x8 pack_bf16x8(f32x4 a, f32x4 b) {
    frag_u f;
    f.u[0] = cvt_pk_bf16(a.x, a.y);
    f.u[1] = cvt_pk_bf16(a.z, a.w);
    f.u[2] = cvt_pk_bf16(b.x, b.y);
    f.u[3] = cvt_pk_bf16(b.z, b.w);
    return f.s;
}

__device__ __forceinline__ uint16_t f32_to_bf16(float v) {
    uint32_t u = __builtin_bit_cast(uint32_t, v);
    return (uint16_t)((u + 0x7FFFu + ((u >> 16) & 1u)) >> 16);
}

// fast tanh: 1 - 2/(e^{2x}+1); saturates correctly for |x| large
__device__ __forceinline__ float tanh_fast(float x) {
    float e = __expf(2.0f * x);
    return 1.0f - 2.0f * __builtin_amdgcn_rcpf(e + 1.0f);
}

__device__ __forceinline__ int imax(int a, int b) { return a > b ? a : b; }
__device__ __forceinline__ int max4(f32x4 v) {
    i32x4 a = __builtin_bit_cast(i32x4, v);
    return imax(imax(a.x, a.y), imax(a.z, a.w));
}

__global__ void rnn_init_kernel(const float* __restrict__ H0,
                                uint16_t* __restrict__ comm) {
    // slot 0 of the ring holds bf16(H0), read by step t=0
    int i = blockIdx.x * 256 + threadIdx.x;
    for (int e = i; e < SLOT; e += 64 * 256)
        comm[e] = f32_to_bf16(H0[e]);
}

__global__ __launch_bounds__(THREADS, 1)
void rnn_seq_kernel(const float* __restrict__ X, const float* __restrict__ Wih,
                    const float* __restrict__ Whh, const float* __restrict__ bh,
                    float* __restrict__ out, uint16_t* __restrict__ comm,
                    int* __restrict__ flags2)
{
    extern __shared__ char lds[];

    const int tid = threadIdx.x;
    const int grp = blockIdx.x >> 4;       // batch group 0..3
    const int p   = blockIdx.x & 15;       // col-slice 0..15
    const int lane = tid & 63, wv = tid >> 6;
    const int cb = lane & 15, kg = lane >> 4;
    const int hc0 = p * 64;                // WG's first col
    const int b   = grp * NB + cb;         // batch row this lane owns

    // ---- One-time: load this wave's W (16 cols x 1152) into 36 reg frags.
    // Two-phase LDS bounce: stage 32 cols in fragment order, waves read, swap.
    // Frag (k,c) for tile ct: byte ((ct*36 + k>>5)<<10) + ((k>>3)&3)<<8
    // + (c&15)<<4 + (k&7)<<1 -> wave frag = (ct*36+kk)*1024 + lane*16.
    s16x8 wreg[36];
    #pragma unroll
    for (int half = 0; half < 2; ++half) {
        for (int e = tid; e < 32 * KTOT; e += THREADS) {
            int c2 = e & 31;
            int k  = e >> 5;
            int hcol = hc0 + half * 32 + c2;
            float w = (k < HID) ? Whh[(size_t)k * HID + hcol]
                                : Wih[(size_t)(k - HID) * HID + hcol];
            uint32_t off = ((uint32_t)((c2 >> 4) * 36 + (k >> 5)) << 10)
                         + (((k >> 3) & 3) << 8) + ((c2 & 15) << 4) + ((k & 7) << 1);
            *(uint16_t*)(lds + off) = f32_to_bf16(w);
        }
        __syncthreads();
        if ((wv >> 1) == half) {
            const char* base = lds + (size_t)(wv & 1) * 36 * 1024 + lane * 16;
            #pragma unroll
            for (int kk = 0; kk < 36; ++kk)
                wreg[kk] = *(const s16x8*)(base + (size_t)kk * 1024);
        }
        __syncthreads();
    }

    // D = mfma(Wfrag, Hfrag): rows = h, cols = batch. Lane owns
    // h = hc0 + wv*16 + kg*4 + {0..3} of batch b.
    const int h = hc0 + wv * 16 + kg * 4;
    const f32x4 bv = *(const f32x4*)(bh + h);

    // transposed private flags: flags2[grp][consumer p][consumer wv][64
    // producer-waves]. Consumer wave polls its own 64-int block.
    const int* fpoll = flags2 + ((grp * NSL + p) * NWAVES + wv) * 64 + lane;
    int* fst = flags2 + ((grp * NSL + (lane & 15)) * NWAVES + (lane >> 4)) * 64
             + (p * NWAVES + wv);

    uint16_t* wb = comm + (size_t)b * HID + h;      // publish/clear base
    float* ob = out + (size_t)b * HID + h;

    // staging geometry: thread covers frags f = i*256+tid, i=0..7;
    // frag f = (cb_f = f&15, kg_f = (f>>4)&3, kk_f = f>>6);
    // LDS dst = Hb + f*16 (fragment order, lane-linear);
    // src = comm_slot + (grp*16 + cb_f)*1024 + kk_f*32 + kg_f*8 (elems).
    const size_t ssrc = (size_t)(grp * NB + (tid & 15)) * HID
                      + ((tid >> 4) & 3) * 8 + (tid >> 6) * 32;

    u32x2 sentv; sentv.x = SENT; sentv.y = SENT;

    for (int t = 0; t < T_STEPS; ++t) {
        f32x4 acc0 = {0.f,0.f,0.f,0.f}, acc1 = {0.f,0.f,0.f,0.f};

        // ---- Phase A: X projection from reg-resident W_ih frags ----
        const float* xrow = X + ((size_t)t * BATCH + b) * IN_DIM;
        #pragma unroll
        for (int kk = 0; kk < NKX; ++kk) {
            int kidx = kk * 32 + kg * 8;
            f32x4 f0 = *(const f32x4*)(xrow + kidx);
            f32x4 f1 = *(const f32x4*)(xrow + kidx + 4);
            s16x8 xf = pack_bf16x8(f0, f1);
            if (kk & 1) acc1 = MFMA16(wreg[32 + kk], xf, acc1, 0, 0, 0);
            else        acc0 = MFMA16(wreg[32 + kk], xf, acc0, 0, 0, 0);
        }
        __builtin_amdgcn_sched_barrier(0);

        // ---- Phase B: poll the 64 producer-wave flags of my group ----
        if (t > 0) {
            for (;;) {
                int f;
                asm volatile("global_load_dword %0, %1, off sc0 sc1\n\t"
                             "s_waitcnt vmcnt(0)"
                             : "=v"(f) : "v"(fpoll) : "memory");
                if (__all(f >= t)) break;
            }
        }
        __builtin_amdgcn_sched_barrier(0);

        // ---- Phase C: cooperative stage of group's H[t] (32 KB) into LDS
        //      fragment-order buffer; sentinel-validate per-thread portion ----
        char* Hb = lds + (size_t)(t & 1) * HBUF;
        const char* gsrc = (const char*)(comm + (size_t)(t & (RING - 1)) * SLOT
                                         + ssrc);
        f32x4 L[8];
        for (;;) {
            #pragma unroll
            for (int i = 0; i < 8; ++i)
                asm volatile("global_load_dwordx4 %0, %1, off sc0 sc1"
                             : "=v"(L[i]) : "v"(gsrc + (size_t)i * 256) : "memory");
            asm volatile("s_waitcnt vmcnt(0)" ::: "memory");
            __builtin_amdgcn_sched_barrier(0);
            int m = (int)0x80000000;
            #pragma unroll
            for (int i = 0; i < 8; ++i) m = imax(m, max4(L[i]));
            if (__all(m != (int)SENT)) break;
        }
        #pragma unroll
        for (int i = 0; i < 8; ++i)
            *(f32x4*)(Hb + tid * 16 + i * 4096) = L[i];
        __syncthreads();                 // H tile ready (double-buffered)

        // ---- recurrent GEMM: K=1024; A=W regs, B=H frags from LDS ----
        const char* hfb = Hb + lane * 16;
        #pragma unroll
        for (int kk = 0; kk < NKH; ++kk) {
            s16x8 af = *(const s16x8*)(hfb + (size_t)kk * 1024);
            if (kk & 1) acc1 = MFMA16(wreg[kk], af, acc1, 0, 0, 0);
            else        acc0 = MFMA16(wreg[kk], af, acc0, 0, 0, 0);
        }

        // ---- Epilogue: bias+tanh; publish 8B; flag (no drain, sentinel
        //      backstop); clear-ahead; fp32 out ----
        float t0 = tanh_fast(acc0[0] + acc1[0] + bv.x);
        float t1 = tanh_fast(acc0[1] + acc1[1] + bv.y);
        float t2 = tanh_fast(acc0[2] + acc1[2] + bv.z);
        float t3 = tanh_fast(acc0[3] + acc1[3] + bv.w);

        u32x2 cd;
        cd.x = cvt_pk_bf16(t0, t1);
        cd.y = cvt_pk_bf16(t2, t3);
        uint16_t* pw = wb + (size_t)((t + 1) & (RING - 1)) * SLOT;
        asm volatile("global_store_dwordx2 %0, %1, off sc0 sc1"
                     :: "v"(pw), "v"(cd) : "memory");
        {
            int fv = t + 1;
            asm volatile("global_store_dword %0, %1, off sc0 sc1"
                         :: "v"(fst), "v"(fv) : "memory");
        }
        {   // re-sentinel slot (t+1+DCLR): landed by next step's vmcnt(0),
            // read DCLR steps later (peer spread <=1 step) -- safe window.
            uint16_t* pc = wb + (size_t)((t + 1 + DCLR) & (RING - 1)) * SLOT;
            asm volatile("global_store_dwordx2 %0, %1, off sc0 sc1"
                         :: "v"(pc), "v"(sentv) : "memory");
        }

        // fp32 states (normal cached 16B store, off the critical path)
        f32x4 vo; vo.x = t0; vo.y = t1; vo.z = t2; vo.w = t3;
        *(f32x4*)(ob + (size_t)t * BATCH * HID) = vo;
        if (t == T_STEPS - 1)
            *(f32x4*)(ob + (size_t)T_STEPS * BATCH * HID) = vo;  // H_final
    }
}

extern "C" void kernel_launch(void* const* d_in, const int* in_sizes, int n_in,
                              void* d_out, int out_size, void* d_ws, size_t ws_size,
                              hipStream_t stream) {
    (void)in_sizes; (void)n_in; (void)out_size; (void)ws_size;
    const float* X   = (const float*)d_in[0];
    const float* Wih = (const float*)d_in[1];
    const float* Whh = (const float*)d_in[2];
    const float* bh  = (const float*)d_in[3];
    const float* H0  = (const float*)d_in[4];
    float* out = (float*)d_out;

    uint16_t* comm = (uint16_t*)d_ws;                             // 2 MB ring
    int* flags2 = (int*)((char*)d_ws + (size_t)RING * SLOT * 2);  // 16384 ints

    hipFuncSetAttribute((const void*)rnn_seq_kernel,
                        hipFuncAttributeMaxDynamicSharedMemorySize, LDSB);

    // sentinel-fill the ring, zero the flags, then bf16(H0) -> slot 0
    hipMemsetAsync(comm, 0x7F, (size_t)RING * SLOT * 2, stream);
    hipMemsetAsync(flags2, 0, NFLAGS * sizeof(int), stream);
    hipLaunchKernelGGL(rnn_init_kernel, dim3(64), dim3(256), 0, stream, H0, comm);
    hipLaunchKernelGGL(rnn_seq_kernel, dim3(NGRP * NSL), dim3(THREADS), LDSB, stream,
                       X, Wih, Whh, bh, out, comm, flags2);
}

// Round 13
// 1741.314 us; speedup vs baseline: 2.1494x; 1.1830x over previous
//
#include <hip/hip_runtime.h>
#include <hip/hip_bf16.h>
#include <stdint.h>

// Problem constants
#define T_STEPS 512
#define BATCH   64
#define IN_DIM  128
#define HID     1024
#define KTOT    (HID + IN_DIM)   // 1152
#define NWAVES  4
#define THREADS (NWAVES * 64)

// 4 independent batch-groups x 16 col-slices. WG = 16 batches x 64 cols.
// Wave w: 16 batches x 16 cols, W in VGPRs (36 frags = 144 regs).
// Group H tile (16 x 1024 bf16 = 32 KB) double-buffered in LDS, shared.
// NO FLAGS: consumers poll the DATA (sentinel ring) -- detection == load.
#define NGRP    4
#define NSL     16               // col-slice WGs per group
#define NB      16               // batches per group
#define NKH     32               // recurrent K-steps (1024/32)
#define NKX     4                // X K-steps (128/32)
#define HBUF    32768            // one H LDS buffer
#define LDSB    73728            // W-stage scratch (also covers 2x32KB H)

#define RING    16               // comm ring slots (2 MB)
#define DCLR    4                // clear-ahead depth
#define SLOT    (BATCH * HID)    // 65536 bf16 = 128 KB per slot
#define SENT    0x7F7F7F7F      // bf16 pair 3.39e38, unreachable by tanh

typedef float f32x4 __attribute__((ext_vector_type(4)));
typedef int   i32x4 __attribute__((ext_vector_type(4)));
typedef short s16x8 __attribute__((ext_vector_type(8)));
typedef uint32_t u32x2 __attribute__((ext_vector_type(2)));

#define MFMA16 __builtin_amdgcn_mfma_f32_16x16x32_bf16

__device__ __forceinline__ uint32_t cvt_pk_bf16(float a, float b) {
    uint32_t r;
    asm("v_cvt_pk_bf16_f32 %0, %1, %2" : "=v"(r) : "v"(a), "v"(b));
    return r;   // low16 = bf16(a), high16 = bf16(b)
}

union frag_u { uint32_t u[4]; s16x8 s; };

__device__ __forceinline__ s16x8 pack_bf16x8(f32x4 a, f32x4 b) {
    frag_u f;
    f.u[0] = cvt_pk_bf16(a.x, a.y);
    f.u[1] = cvt_pk_bf16(a.z, a.w);
    f.u[2] = cvt_pk_bf16(b.x, b.y);
    f.u[3] = cvt_pk_bf16(b.z, b.w);
    return f.s;
}

__device__ __forceinline__ uint16_t f32_to_bf16(float v) {
    uint32_t u = __builtin_bit_cast(uint32_t, v);
    return (uint16_t)((u + 0x7FFFu + ((u >> 16) & 1u)) >> 16);
}

// fast tanh: 1 - 2/(e^{2x}+1); saturates correctly for |x| large
__device__ __forceinline__ float tanh_fast(float x) {
    float e = __expf(2.0f * x);
    return 1.0f - 2.0f * __builtin_amdgcn_rcpf(e + 1.0f);
}

__device__ __forceinline__ int imax(int a, int b) { return a > b ? a : b; }
__device__ __forceinline__ int max4(f32x4 v) {
    i32x4 a = __builtin_bit_cast(i32x4, v);
    return imax(imax(a.x, a.y), imax(a.z, a.w));
}

__global__ void rnn_init_kernel(const float* __restrict__ H0,
                                uint16_t* __restrict__ comm) {
    // slot 0 of the ring holds bf16(H0), read by step t=0
    int i = blockIdx.x * 256 + threadIdx.x;
    for (int e = i; e < SLOT; e += 64 * 256)
        comm[e] = f32_to_bf16(H0[e]);
}

__global__ __launch_bounds__(THREADS, 1)
void rnn_seq_kernel(const float* __restrict__ X, const float* __restrict__ Wih,
                    const float* __restrict__ Whh, const float* __restrict__ bh,
                    float* __restrict__ out, uint16_t* __restrict__ comm)
{
    extern __shared__ char lds[];

    const int tid = threadIdx.x;
    const int grp = blockIdx.x >> 4;       // batch group 0..3
    const int p   = blockIdx.x & 15;       // col-slice 0..15
    const int lane = tid & 63, wv = tid >> 6;
    const int cb = lane & 15, kg = lane >> 4;
    const int hc0 = p * 64;                // WG's first col
    const int b   = grp * NB + cb;         // batch row this lane owns

    // ---- One-time: load this wave's W (16 cols x 1152) into 36 reg frags.
    // Two-phase LDS bounce (fragment order, lane-linear, bijective).
    s16x8 wreg[36];
    #pragma unroll
    for (int half = 0; half < 2; ++half) {
        for (int e = tid; e < 32 * KTOT; e += THREADS) {
            int c2 = e & 31;
            int k  = e >> 5;
            int hcol = hc0 + half * 32 + c2;
            float w = (k < HID) ? Whh[(size_t)k * HID + hcol]
                                : Wih[(size_t)(k - HID) * HID + hcol];
            uint32_t off = ((uint32_t)((c2 >> 4) * 36 + (k >> 5)) << 10)
                         + (((k >> 3) & 3) << 8) + ((c2 & 15) << 4) + ((k & 7) << 1);
            *(uint16_t*)(lds + off) = f32_to_bf16(w);
        }
        __syncthreads();
        if ((wv >> 1) == half) {
            const char* base = lds + (size_t)(wv & 1) * 36 * 1024 + lane * 16;
            #pragma unroll
            for (int kk = 0; kk < 36; ++kk)
                wreg[kk] = *(const s16x8*)(base + (size_t)kk * 1024);
        }
        __syncthreads();
    }

    // D = mfma(Wfrag, Hfrag): rows = h, cols = batch. Lane owns
    // h = hc0 + wv*16 + kg*4 + {0..3} of batch b.
    const int h = hc0 + wv * 16 + kg * 4;
    const f32x4 bv = *(const f32x4*)(bh + h);

    uint16_t* wb = comm + (size_t)b * HID + h;      // publish/clear base
    float* ob = out + (size_t)b * HID + h;

    // staging geometry: thread covers frags f = i*256+tid, i=0..7;
    // LDS dst = Hb + f*16 (fragment order, lane-linear);
    // src = comm_slot + (grp*16 + (tid&15))*1024 + (tid>>6)*32 + ((tid>>4)&3)*8.
    const size_t ssrc = (size_t)(grp * NB + (tid & 15)) * HID
                      + ((tid >> 4) & 3) * 8 + (tid >> 6) * 32;

    u32x2 sentv; sentv.x = SENT; sentv.y = SENT;

    for (int t = 0; t < T_STEPS; ++t) {
        f32x4 acc0 = {0.f,0.f,0.f,0.f}, acc1 = {0.f,0.f,0.f,0.f};

        // ---- Phase A: X projection from reg-resident W_ih frags ----
        const float* xrow = X + ((size_t)t * BATCH + b) * IN_DIM;
        #pragma unroll
        for (int kk = 0; kk < NKX; ++kk) {
            int kidx = kk * 32 + kg * 8;
            f32x4 f0 = *(const f32x4*)(xrow + kidx);
            f32x4 f1 = *(const f32x4*)(xrow + kidx + 4);
            s16x8 xf = pack_bf16x8(f0, f1);
            if (kk & 1) acc1 = MFMA16(wreg[32 + kk], xf, acc1, 0, 0, 0);
            else        acc0 = MFMA16(wreg[32 + kk], xf, acc0, 0, 0, 0);
        }
        __builtin_amdgcn_sched_barrier(0);

        // ---- Phase B+C fused: poll the DATA of my staging portion (128 B)
        //      until sentinel-free; detection IS the load ----
        char* Hb = lds + (size_t)(t & 1) * HBUF;
        const char* gsrc = (const char*)(comm + (size_t)(t & (RING - 1)) * SLOT
                                         + ssrc);
        f32x4 L[8];
        for (;;) {
            #pragma unroll
            for (int i = 0; i < 8; ++i)
                asm volatile("global_load_dwordx4 %0, %1, off sc0 sc1"
                             : "=v"(L[i]) : "v"(gsrc + (size_t)i * 256) : "memory");
            asm volatile("s_waitcnt vmcnt(0)" ::: "memory");
            __builtin_amdgcn_sched_barrier(0);
            int m = (int)0x80000000;
            #pragma unroll
            for (int i = 0; i < 8; ++i) m = imax(m, max4(L[i]));
            if (__all(m != (int)SENT)) break;
        }
        #pragma unroll
        for (int i = 0; i < 8; ++i)
            *(f32x4*)(Hb + tid * 16 + i * 4096) = L[i];
        __syncthreads();                 // H tile ready (double-buffered)

        // ---- recurrent GEMM: K=1024; A=W regs, B=H frags from LDS ----
        const char* hfb = Hb + lane * 16;
        #pragma unroll
        for (int kk = 0; kk < NKH; ++kk) {
            s16x8 af = *(const s16x8*)(hfb + (size_t)kk * 1024);
            if (kk & 1) acc1 = MFMA16(wreg[kk], af, acc1, 0, 0, 0);
            else        acc0 = MFMA16(wreg[kk], af, acc0, 0, 0, 0);
        }

        // ---- Epilogue: bias+tanh; publish 8B (no flag, no drain);
        //      clear-ahead; fp32 out ----
        float t0 = tanh_fast(acc0[0] + acc1[0] + bv.x);
        float t1 = tanh_fast(acc0[1] + acc1[1] + bv.y);
        float t2 = tanh_fast(acc0[2] + acc1[2] + bv.z);
        float t3 = tanh_fast(acc0[3] + acc1[3] + bv.w);

        u32x2 cd;
        cd.x = cvt_pk_bf16(t0, t1);
        cd.y = cvt_pk_bf16(t2, t3);
        uint16_t* pw = wb + (size_t)((t + 1) & (RING - 1)) * SLOT;
        asm volatile("global_store_dwordx2 %0, %1, off sc0 sc1"
                     :: "v"(pw), "v"(cd) : "memory");
        {   // re-sentinel slot (t+1+DCLR): lands well before it is read
            // DCLR steps later (within-group spread <=1 by data dependency;
            // groups touch disjoint bytes).
            uint16_t* pc = wb + (size_t)((t + 1 + DCLR) & (RING - 1)) * SLOT;
            asm volatile("global_store_dwordx2 %0, %1, off sc0 sc1"
                         :: "v"(pc), "v"(sentv) : "memory");
        }

        // fp32 states (normal cached 16B store, off the critical path)
        f32x4 vo; vo.x = t0; vo.y = t1; vo.z = t2; vo.w = t3;
        *(f32x4*)(ob + (size_t)t * BATCH * HID) = vo;
        if (t == T_STEPS - 1)
            *(f32x4*)(ob + (size_t)T_STEPS * BATCH * HID) = vo;  // H_final
    }
}

extern "C" void kernel_launch(void* const* d_in, const int* in_sizes, int n_in,
                              void* d_out, int out_size, void* d_ws, size_t ws_size,
                              hipStream_t stream) {
    (void)in_sizes; (void)n_in; (void)out_size; (void)ws_size;
    const float* X   = (const float*)d_in[0];
    const float* Wih = (const float*)d_in[1];
    const float* Whh = (const float*)d_in[2];
    const float* bh  = (const float*)d_in[3];
    const float* H0  = (const float*)d_in[4];
    float* out = (float*)d_out;

    uint16_t* comm = (uint16_t*)d_ws;    // RING * SLOT bf16 = 2 MB

    hipFuncSetAttribute((const void*)rnn_seq_kernel,
                        hipFuncAttributeMaxDynamicSharedMemorySize, LDSB);

    // sentinel-fill the ring, then bf16(H0) -> slot 0
    hipMemsetAsync(comm, 0x7F, (size_t)RING * SLOT * 2, stream);
    hipLaunchKernelGGL(rnn_init_kernel, dim3(64), dim3(256), 0, stream, H0, comm);
    hipLaunchKernelGGL(rnn_seq_kernel, dim3(NGRP * NSL), dim3(THREADS), LDSB, stream,
                       X, Wih, Whh, bh, out, comm);
}